// Round 1
// baseline (343.728 us; speedup 1.0000x reference)
//
#include <hip/hip_runtime.h>

#define BATCH 16
#define TLEN 4096
#define SDIM 256      // state dim = input dim = output dim = 256
#define CHUNK 128     // scan chunk length
#define NCHUNK (TLEN / CHUNK)          // 32
#define MTOT (BATCH * TLEN)            // 65536

// ---------------------------------------------------------------------------
// Tiled fp32 GEMM: Cout[M][256] = A[M][256] * B[256][256], row-major.
// 128x128 tile, BK=16, 256 threads, 8x8 micro-tile.
// ---------------------------------------------------------------------------
__global__ __launch_bounds__(256) void gemm256(const float* __restrict__ A,
                                               const float* __restrict__ B,
                                               float* __restrict__ Cout) {
    const int K = 256, N = 256;
    __shared__ __align__(16) float As[16][128];   // [k][m]
    __shared__ __align__(16) float Bs[16][128];   // [k][n]

    const int m0 = blockIdx.x * 128;
    const int n0 = blockIdx.y * 128;
    const int tid = threadIdx.x;
    const int ty = tid >> 4;          // 0..15
    const int tx = tid & 15;          // 0..15

    float acc[8][8] = {};

    for (int k0 = 0; k0 < K; k0 += 16) {
        // ---- stage A tile (128 rows x 16 k) transposed into As[k][m]
#pragma unroll
        for (int i = 0; i < 2; ++i) {
            int f = tid + i * 256;            // 0..511 float4 index
            int r = f >> 2;                   // 0..127
            int c4 = (f & 3) << 2;            // 0,4,8,12
            const float4 v = *reinterpret_cast<const float4*>(
                &A[(size_t)(m0 + r) * K + (k0 + c4)]);
            As[c4 + 0][r] = v.x;
            As[c4 + 1][r] = v.y;
            As[c4 + 2][r] = v.z;
            As[c4 + 3][r] = v.w;
        }
        // ---- stage B tile (16 k x 128 n)
#pragma unroll
        for (int i = 0; i < 2; ++i) {
            int f = tid + i * 256;
            int r = f >> 5;                   // 0..15
            int c4 = (f & 31) << 2;           // 0..124
            const float4 v = *reinterpret_cast<const float4*>(
                &B[(size_t)(k0 + r) * N + (n0 + c4)]);
            *reinterpret_cast<float4*>(&Bs[r][c4]) = v;
        }
        __syncthreads();

#pragma unroll
        for (int kk = 0; kk < 16; ++kk) {
            float a[8], b[8];
            *reinterpret_cast<float4*>(&a[0]) =
                *reinterpret_cast<const float4*>(&As[kk][ty * 8]);
            *reinterpret_cast<float4*>(&a[4]) =
                *reinterpret_cast<const float4*>(&As[kk][ty * 8 + 4]);
            *reinterpret_cast<float4*>(&b[0]) =
                *reinterpret_cast<const float4*>(&Bs[kk][tx * 8]);
            *reinterpret_cast<float4*>(&b[4]) =
                *reinterpret_cast<const float4*>(&Bs[kk][tx * 8 + 4]);
#pragma unroll
            for (int i = 0; i < 8; ++i)
#pragma unroll
                for (int j = 0; j < 8; ++j)
                    acc[i][j] = fmaf(a[i], b[j], acc[i][j]);
        }
        __syncthreads();
    }

#pragma unroll
    for (int i = 0; i < 8; ++i) {
        size_t row = (size_t)(m0 + ty * 8 + i);
        float4 v0 = {acc[i][0], acc[i][1], acc[i][2], acc[i][3]};
        float4 v1 = {acc[i][4], acc[i][5], acc[i][6], acc[i][7]};
        *reinterpret_cast<float4*>(&Cout[row * N + n0 + tx * 8])     = v0;
        *reinterpret_cast<float4*>(&Cout[row * N + n0 + tx * 8 + 4]) = v1;
    }
}

// ---------------------------------------------------------------------------
// Phase 1: per-chunk zero-init local scan end E[b][k][s]
// ---------------------------------------------------------------------------
__global__ __launch_bounds__(256) void chunk_summary(const float* __restrict__ Bu,
                                                     const float* __restrict__ A,
                                                     float* __restrict__ E) {
    const int b = blockIdx.x >> 5;       // /NCHUNK
    const int k = blockIdx.x & 31;
    const int s = threadIdx.x;
    const float a = A[s];
    float h = 0.f;
    const float* p = Bu + ((size_t)b * TLEN + (size_t)k * CHUNK) * SDIM + s;
#pragma unroll 8
    for (int t = 0; t < CHUNK; ++t)
        h = fmaf(h, a, p[(size_t)t * SDIM]);
    E[((size_t)b * NCHUNK + k) * SDIM + s] = h;
}

// ---------------------------------------------------------------------------
// Phase 2: inter-chunk carries. H[b][k][s] = global h just before chunk k.
//   H[b][0] = h0 ; H[b][k] = a^CHUNK * H[b][k-1] + E[b][k-1]
// ---------------------------------------------------------------------------
__global__ __launch_bounds__(256) void carries(const float* __restrict__ E,
                                               const float* __restrict__ A,
                                               const float* __restrict__ h0,
                                               float* __restrict__ H) {
    const int b = blockIdx.x;
    const int s = threadIdx.x;
    const float a = A[s];
    float aL = 1.f;
    for (int i = 0; i < CHUNK; ++i) aL *= a;
    float h = h0[s];
    for (int k = 0; k < NCHUNK; ++k) {
        H[((size_t)b * NCHUNK + k) * SDIM + s] = h;
        h = fmaf(h, aL, E[((size_t)b * NCHUNK + k) * SDIM + s]);
    }
}

// ---------------------------------------------------------------------------
// Phase 3: full scan with correct carry-in, in place (Bu -> h states).
// ---------------------------------------------------------------------------
__global__ __launch_bounds__(256) void scan_apply(float* __restrict__ Bu,
                                                  const float* __restrict__ A,
                                                  const float* __restrict__ H) {
    const int b = blockIdx.x >> 5;
    const int k = blockIdx.x & 31;
    const int s = threadIdx.x;
    const float a = A[s];
    float h = H[((size_t)b * NCHUNK + k) * SDIM + s];
    float* p = Bu + ((size_t)b * TLEN + (size_t)k * CHUNK) * SDIM + s;
#pragma unroll 8
    for (int t = 0; t < CHUNK; ++t) {
        h = fmaf(h, a, p[(size_t)t * SDIM]);
        p[(size_t)t * SDIM] = h;
    }
}

// ---------------------------------------------------------------------------
extern "C" void kernel_launch(void* const* d_in, const int* in_sizes, int n_in,
                              void* d_out, int out_size, void* d_ws, size_t ws_size,
                              hipStream_t stream) {
    const float* X  = (const float*)d_in[0];   // [16,4096,256]
    const float* A  = (const float*)d_in[1];   // [256]
    const float* Bm = (const float*)d_in[2];   // [256,256]
    const float* Cm = (const float*)d_in[3];   // [256,256]
    const float* h0 = (const float*)d_in[4];   // [256]
    float* Y   = (float*)d_out;                // [16,4096,256]

    float* ws0 = (float*)d_ws;                         // Bu / h buffer: 64 MB
    float* E   = ws0 + (size_t)MTOT * SDIM;            // 512 KB
    float* H   = E + (size_t)BATCH * NCHUNK * SDIM;    // 512 KB

    dim3 gGemm(MTOT / 128, 256 / 128);

    // Bu = X @ B
    gemm256<<<gGemm, 256, 0, stream>>>(X, Bm, ws0);
    // chunked diagonal scan (h0 honored)
    chunk_summary<<<BATCH * NCHUNK, 256, 0, stream>>>(ws0, A, E);
    carries<<<BATCH, 256, 0, stream>>>(E, A, h0, H);
    scan_apply<<<BATCH * NCHUNK, 256, 0, stream>>>(ws0, A, H);
    // Y = h @ C
    gemm256<<<gGemm, 256, 0, stream>>>(ws0, Cm, Y);
}

// Round 3
// 219.283 us; speedup vs baseline: 1.5675x; 1.5675x over previous
//
#include <hip/hip_runtime.h>

typedef _Float16 f16;
typedef _Float16 f16x8 __attribute__((ext_vector_type(8)));
typedef _Float16 f16x4 __attribute__((ext_vector_type(4)));
typedef float f32x4 __attribute__((ext_vector_type(4)));
typedef float f32x16 __attribute__((ext_vector_type(16)));

#define BATCH 16
#define TLEN 4096
#define SDIM 256
#define MTOT (BATCH * TLEN)      // 65536
#define CHUNK 64
#define NCHUNK (TLEN / CHUNK)    // 64

#define BM 128
#define BN 128
#define BK 32
#define LDK 40                   // padded LDS row stride (halfs): 80 B, 16B-aligned

// ---------------------------------------------------------------------------
// Transpose + fp16 split: Th/Tl[n][k] = split(M[k][n]) for a 256x256 matrix.
// ---------------------------------------------------------------------------
__global__ __launch_bounds__(256) void tsplit(const float* __restrict__ M,
                                              f16* __restrict__ Th,
                                              f16* __restrict__ Tl) {
    __shared__ float t[64][65];
    const int r0 = blockIdx.x * 64, c0 = blockIdx.y * 64;
    const int cc = threadIdx.x & 63, rr = threadIdx.x >> 6;
#pragma unroll
    for (int i = 0; i < 16; ++i) {
        int r = i * 4 + rr;
        t[r][cc] = M[(size_t)(r0 + r) * 256 + c0 + cc];
    }
    __syncthreads();
#pragma unroll
    for (int i = 0; i < 16; ++i) {
        int n = i * 4 + rr;                 // column of M == row of T
        float v = t[cc][n];
        f16 h = (f16)v;
        f16 l = (f16)(v - (float)h);
        Th[(size_t)(c0 + n) * 256 + r0 + cc] = h;
        Tl[(size_t)(c0 + n) * 256 + r0 + cc] = l;
    }
}

// ---------------------------------------------------------------------------
// MFMA GEMM: Out[M][256] = Ain[M][256] (fp32) * B (given as fp16 hi/lo B^T[n][k]).
// fp16 2-way split, 3 products -> ~22-bit effective mantissa.
// 128x128 tile, BK=32, 4 waves, 32x32x16 MFMA, 2x2 frags/wave.
// ---------------------------------------------------------------------------
__global__ __launch_bounds__(256) void gemm_mfma(const float* __restrict__ Ain,
                                                 const f16* __restrict__ BhT,
                                                 const f16* __restrict__ BlT,
                                                 float* __restrict__ Out) {
    __shared__ f16 Ah[BM][LDK], Al[BM][LDK], Bh[BN][LDK], Bl[BN][LDK];

    const int m0 = blockIdx.x * BM, n0 = blockIdx.y * BN;
    const int tid = threadIdx.x;
    const int wid = tid >> 6, lane = tid & 63;
    const int wm = (wid & 1) * 64, wn = (wid >> 1) * 64;
    const int lr = lane & 31;            // row/col within 32x32 frag
    const int kg8 = (lane >> 5) * 8;     // k sub-offset within 16-k slice
    const int lh = lane >> 5;

    f32x16 acc[2][2] = {};

    // ---- prefetch registers
    float4 pa[4];
    f16x8 pbh[2], pbl[2];

    auto load_g = [&](int k0) {
#pragma unroll
        for (int i = 0; i < 4; ++i) {
            int f = i * 256 + tid;
            int r = f >> 3, kq = (f & 7) * 4;
            pa[i] = *reinterpret_cast<const float4*>(
                &Ain[(size_t)(m0 + r) * 256 + k0 + kq]);
        }
#pragma unroll
        for (int i = 0; i < 2; ++i) {
            int f = i * 256 + tid;
            int r = f >> 2, ko = (f & 3) * 8;
            pbh[i] = *reinterpret_cast<const f16x8*>(
                &BhT[(size_t)(n0 + r) * 256 + k0 + ko]);
            pbl[i] = *reinterpret_cast<const f16x8*>(
                &BlT[(size_t)(n0 + r) * 256 + k0 + ko]);
        }
    };

    load_g(0);

    for (int ks = 0; ks < 256 / BK; ++ks) {
        // ---- write staged regs to LDS (split A on the fly)
#pragma unroll
        for (int i = 0; i < 4; ++i) {
            int f = i * 256 + tid;
            int r = f >> 3, kq = (f & 7) * 4;
            const float* xs = reinterpret_cast<const float*>(&pa[i]);
            f16x4 hv, lv;
#pragma unroll
            for (int c = 0; c < 4; ++c) {
                float x = xs[c];
                f16 h = (f16)x;
                hv[c] = h;
                lv[c] = (f16)(x - (float)h);
            }
            *reinterpret_cast<f16x4*>(&Ah[r][kq]) = hv;
            *reinterpret_cast<f16x4*>(&Al[r][kq]) = lv;
        }
#pragma unroll
        for (int i = 0; i < 2; ++i) {
            int f = i * 256 + tid;
            int r = f >> 2, ko = (f & 3) * 8;
            *reinterpret_cast<f16x8*>(&Bh[r][ko]) = pbh[i];
            *reinterpret_cast<f16x8*>(&Bl[r][ko]) = pbl[i];
        }
        __syncthreads();

        if (ks < 256 / BK - 1) load_g((ks + 1) * BK);   // overlap next loads w/ MFMA

#pragma unroll
        for (int sl = 0; sl < 2; ++sl) {                // two 16-k slices of BK=32
            const int ko = sl * 16 + kg8;
            f16x8 a_h[2], a_l[2], b_h[2], b_l[2];
#pragma unroll
            for (int q = 0; q < 2; ++q) {
                a_h[q] = *reinterpret_cast<const f16x8*>(&Ah[wm + q * 32 + lr][ko]);
                a_l[q] = *reinterpret_cast<const f16x8*>(&Al[wm + q * 32 + lr][ko]);
                b_h[q] = *reinterpret_cast<const f16x8*>(&Bh[wn + q * 32 + lr][ko]);
                b_l[q] = *reinterpret_cast<const f16x8*>(&Bl[wn + q * 32 + lr][ko]);
            }
#pragma unroll
            for (int i = 0; i < 2; ++i)
#pragma unroll
                for (int j = 0; j < 2; ++j) {
                    acc[i][j] = __builtin_amdgcn_mfma_f32_32x32x16_f16(
                        a_h[i], b_h[j], acc[i][j], 0, 0, 0);
                    acc[i][j] = __builtin_amdgcn_mfma_f32_32x32x16_f16(
                        a_h[i], b_l[j], acc[i][j], 0, 0, 0);
                    acc[i][j] = __builtin_amdgcn_mfma_f32_32x32x16_f16(
                        a_l[i], b_h[j], acc[i][j], 0, 0, 0);
                }
        }
        __syncthreads();
    }

    // ---- epilogue: C/D layout col=lane&31, row=(g&3)+8*(g>>2)+4*(lane>>5)
#pragma unroll
    for (int i = 0; i < 2; ++i)
#pragma unroll
        for (int j = 0; j < 2; ++j)
#pragma unroll
            for (int g = 0; g < 16; ++g) {
                int row = m0 + wm + i * 32 + (g & 3) + 8 * (g >> 2) + 4 * lh;
                int col = n0 + wn + j * 32 + lr;
                Out[(size_t)row * 256 + col] = acc[i][j][g];
            }
}

// ---------------------------------------------------------------------------
// Scan phase 1: per-chunk zero-init local end E. One wave per (b,chunk),
// each lane owns 4 states (float4) -> fully coalesced 1KB/row.
// ---------------------------------------------------------------------------
__global__ __launch_bounds__(256) void chunk_summary(const float* __restrict__ Bu,
                                                     const float* __restrict__ A,
                                                     float* __restrict__ E) {
    const int cid = blockIdx.x * 4 + (threadIdx.x >> 6);
    const int lane = threadIdx.x & 63;
    const int b = cid >> 6, k = cid & (NCHUNK - 1);
    const f32x4 a = *reinterpret_cast<const f32x4*>(&A[lane * 4]);
    f32x4 h = {0.f, 0.f, 0.f, 0.f};
    const float* p = Bu + ((size_t)b * TLEN + (size_t)k * CHUNK) * SDIM + lane * 4;
#pragma unroll 8
    for (int t = 0; t < CHUNK; ++t) {
        f32x4 v = *reinterpret_cast<const f32x4*>(p + (size_t)t * SDIM);
        h = h * a + v;
    }
    *reinterpret_cast<f32x4*>(&E[(size_t)cid * SDIM + lane * 4]) = h;
}

// ---------------------------------------------------------------------------
// Scan phase 2: inter-chunk carries. H[b][k] = state entering chunk k.
// ---------------------------------------------------------------------------
__global__ __launch_bounds__(256) void carries(const float* __restrict__ E,
                                               const float* __restrict__ A,
                                               const float* __restrict__ h0f,
                                               float* __restrict__ H) {
    const int b = blockIdx.x, s = threadIdx.x;
    const float a = A[s];
    float aL = a;
#pragma unroll
    for (int i = 0; i < 6; ++i) aL *= aL;   // a^64
    float h = h0f[s];
    for (int k = 0; k < NCHUNK; ++k) {
        H[((size_t)b * NCHUNK + k) * SDIM + s] = h;
        h = fmaf(h, aL, E[((size_t)b * NCHUNK + k) * SDIM + s]);
    }
}

// ---------------------------------------------------------------------------
// Scan phase 3: re-scan with carry-in, in place (Bu -> h states).
// ---------------------------------------------------------------------------
__global__ __launch_bounds__(256) void scan_apply(float* __restrict__ Bu,
                                                  const float* __restrict__ A,
                                                  const float* __restrict__ H) {
    const int cid = blockIdx.x * 4 + (threadIdx.x >> 6);
    const int lane = threadIdx.x & 63;
    const int b = cid >> 6, k = cid & (NCHUNK - 1);
    const f32x4 a = *reinterpret_cast<const f32x4*>(&A[lane * 4]);
    f32x4 h = *reinterpret_cast<const f32x4*>(&H[(size_t)cid * SDIM + lane * 4]);
    float* p = Bu + ((size_t)b * TLEN + (size_t)k * CHUNK) * SDIM + lane * 4;
#pragma unroll 8
    for (int t = 0; t < CHUNK; ++t) {
        f32x4 v = *reinterpret_cast<const f32x4*>(p + (size_t)t * SDIM);
        h = h * a + v;
        *reinterpret_cast<f32x4*>(p + (size_t)t * SDIM) = h;
    }
}

// ---------------------------------------------------------------------------
extern "C" void kernel_launch(void* const* d_in, const int* in_sizes, int n_in,
                              void* d_out, int out_size, void* d_ws, size_t ws_size,
                              hipStream_t stream) {
    const float* X  = (const float*)d_in[0];   // [16,4096,256]
    const float* Av = (const float*)d_in[1];   // [256]
    const float* Bm = (const float*)d_in[2];   // [256,256]
    const float* Cm = (const float*)d_in[3];   // [256,256]
    const float* h0 = (const float*)d_in[4];   // [256]
    float* Y = (float*)d_out;                  // [16,4096,256]

    // ws: Bu (64 MB) + C^T hi/lo (256 KB)  -- within footprint proven in R1
    float* Bu = (float*)d_ws;
    f16* ChT = (f16*)((char*)d_ws + (size_t)MTOT * SDIM * 4);
    f16* ClT = ChT + 256 * 256;

    // d_out doubles as scratch for B^T hi/lo + E + H; all dead before the
    // final GEMM overwrites every byte of d_out with Y.
    f16* BhT = (f16*)d_out;
    f16* BlT = BhT + 256 * 256;
    float* E = (float*)((char*)d_out + (1 << 20));
    float* H = E + (size_t)BATCH * NCHUNK * SDIM;

    tsplit<<<dim3(4, 4), 256, 0, stream>>>(Bm, BhT, BlT);
    tsplit<<<dim3(4, 4), 256, 0, stream>>>(Cm, ChT, ClT);

    // Bu = X @ B   (fp16-split MFMA)
    gemm_mfma<<<dim3(MTOT / BM, 256 / BN), 256, 0, stream>>>(X, BhT, BlT, Bu);

    // chunked diagonal scan (h0 honored)
    chunk_summary<<<BATCH * NCHUNK / 4, 256, 0, stream>>>(Bu, Av, E);
    carries<<<BATCH, 256, 0, stream>>>(E, Av, h0, H);
    scan_apply<<<BATCH * NCHUNK / 4, 256, 0, stream>>>(Bu, Av, H);

    // Y = h @ C
    gemm_mfma<<<dim3(MTOT / BM, 256 / BN), 256, 0, stream>>>(Bu, ChT, ClT, Y);
}

// Round 6
// 193.603 us; speedup vs baseline: 1.7754x; 1.1326x over previous
//
#include <hip/hip_runtime.h>

typedef _Float16 f16;
typedef _Float16 f16x8 __attribute__((ext_vector_type(8)));
typedef _Float16 f16x4 __attribute__((ext_vector_type(4)));
typedef float f32x4 __attribute__((ext_vector_type(4)));
typedef float f32x16 __attribute__((ext_vector_type(16)));

#define BATCH 16
#define TLEN 4096
#define SDIM 256
#define MTOT (BATCH * TLEN)        // 65536
#define CHUNK 128                  // scan chunk == M-tile
#define NCHUNK (TLEN / CHUNK)      // 32 per batch
#define NCHTOT (MTOT / CHUNK)      // 512 total
#define LDK 40                     // padded LDS row stride (halfs)

// ---------------------------------------------------------------------------
// Transpose + fp16 split: Th/Tl[n][k] = split(M[k][n]) for 256x256.
// ---------------------------------------------------------------------------
__global__ __launch_bounds__(256) void tsplit(const float* __restrict__ M,
                                              f16* __restrict__ Th,
                                              f16* __restrict__ Tl) {
    __shared__ float t[64][65];
    const int r0 = blockIdx.x * 64, c0 = blockIdx.y * 64;
    const int cc = threadIdx.x & 63, rr = threadIdx.x >> 6;
#pragma unroll
    for (int i = 0; i < 16; ++i) {
        int r = i * 4 + rr;
        t[r][cc] = M[(size_t)(r0 + r) * 256 + c0 + cc];
    }
    __syncthreads();
#pragma unroll
    for (int i = 0; i < 16; ++i) {
        int n = i * 4 + rr;
        float v = t[cc][n];
        f16 h = (f16)v;
        f16 l = (f16)(v - (float)h);
        Th[(size_t)(c0 + n) * 256 + r0 + cc] = h;
        Tl[(size_t)(c0 + n) * 256 + r0 + cc] = l;
    }
}

// ---------------------------------------------------------------------------
// powA[p][s] = A[s]^(p+1), p = 0..127. One block, coalesced row stores.
// ---------------------------------------------------------------------------
__global__ __launch_bounds__(256) void powA_kernel(const float* __restrict__ A,
                                                   float* __restrict__ P) {
    const int s = threadIdx.x;
    float a = A[s], pw = 1.f;
    for (int p = 0; p < CHUNK; ++p) {
        pw *= a;
        P[(size_t)p * SDIM + s] = pw;
    }
}

// ---------------------------------------------------------------------------
// Inter-chunk carries: H[b*32+k][s] = state entering chunk k of batch b.
// ---------------------------------------------------------------------------
__global__ __launch_bounds__(256) void carries(const float* __restrict__ E,
                                               const float* __restrict__ A,
                                               const float* __restrict__ h0,
                                               float* __restrict__ H) {
    const int b = blockIdx.x, s = threadIdx.x;
    const float a = A[s];
    float aL = a;
#pragma unroll
    for (int i = 0; i < 7; ++i) aL *= aL;   // a^128
    float h = h0[s];
    for (int k = 0; k < NCHUNK; ++k) {
        size_t idx = ((size_t)b * NCHUNK + k) * SDIM + s;
        H[idx] = h;
        h = fmaf(h, aL, E[idx]);
    }
}

// ---------------------------------------------------------------------------
// K1: Bu-tile GEMM (X@B, fp16-split MFMA) fused with chunk-local scan.
// 512 thr (8 waves, 2M x 4N of 64x64), BM=128, BN=256, BK=32.
// Epilogue: acc -> LDS (two 128-col halves), 4-segment parallel column scan,
// write h_local (zero-init chunk scan) + chunk-end E.
// ---------------------------------------------------------------------------
__global__ __launch_bounds__(512, 4) void k1_gemm_scan(
    const float* __restrict__ X, const f16* __restrict__ BhT,
    const f16* __restrict__ BlT, const float* __restrict__ Av,
    float* __restrict__ HL, float* __restrict__ E) {
    __shared__ __align__(16) unsigned char smem[65536];   // staging | hbuf union
    __shared__ float segends[4][128];
    f16 (*Ah)[LDK] = (f16(*)[LDK])(smem);                 // 128*40*2 = 10240
    f16 (*Al)[LDK] = (f16(*)[LDK])(smem + 10240);
    f16 (*Bh)[LDK] = (f16(*)[LDK])(smem + 20480);         // 256*40*2 = 20480
    f16 (*Bl)[LDK] = (f16(*)[LDK])(smem + 40960);
    float (*hbuf)[128] = (float(*)[128])(smem);           // 128*128*4 = 64KB

    const int ch = blockIdx.x;          // global chunk 0..511
    const int row0 = ch * CHUNK;
    const int tid = threadIdx.x;
    const int wid = tid >> 6, lane = tid & 63;
    const int wm = (wid & 1) * 64, wn = (wid >> 1) * 64;
    const int lr = lane & 31, kg8 = (lane >> 5) * 8, lh = lane >> 5;

    f32x16 acc[2][2] = {};

    for (int ks = 0; ks < 8; ++ks) {
        const int k0 = ks * 32;
        float4 xa[2];
        f16x8 bh[2], bl[2];
#pragma unroll
        for (int i = 0; i < 2; ++i) {
            int f = i * 512 + tid;
            int r = f >> 3, kq = (f & 7) * 4;
            xa[i] = *reinterpret_cast<const float4*>(
                &X[(size_t)(row0 + r) * SDIM + k0 + kq]);
        }
#pragma unroll
        for (int i = 0; i < 2; ++i) {
            int f = i * 512 + tid;
            int r = f >> 2, ko = (f & 3) * 8;
            bh[i] = *reinterpret_cast<const f16x8*>(&BhT[(size_t)r * SDIM + k0 + ko]);
            bl[i] = *reinterpret_cast<const f16x8*>(&BlT[(size_t)r * SDIM + k0 + ko]);
        }
        __syncthreads();   // previous MFMA (or nothing) done before LDS overwrite
#pragma unroll
        for (int i = 0; i < 2; ++i) {
            int f = i * 512 + tid;
            int r = f >> 3, kq = (f & 7) * 4;
            const float* xs = reinterpret_cast<const float*>(&xa[i]);
            f16x4 hv, lv;
#pragma unroll
            for (int c = 0; c < 4; ++c) {
                float x = xs[c];
                f16 h = (f16)x;
                hv[c] = h;
                lv[c] = (f16)(x - (float)h);
            }
            *reinterpret_cast<f16x4*>(&Ah[r][kq]) = hv;
            *reinterpret_cast<f16x4*>(&Al[r][kq]) = lv;
        }
#pragma unroll
        for (int i = 0; i < 2; ++i) {
            int f = i * 512 + tid;
            int r = f >> 2, ko = (f & 3) * 8;
            *reinterpret_cast<f16x8*>(&Bh[r][ko]) = bh[i];
            *reinterpret_cast<f16x8*>(&Bl[r][ko]) = bl[i];
        }
        __syncthreads();
#pragma unroll
        for (int sl = 0; sl < 2; ++sl) {
            const int ko = sl * 16 + kg8;
            f16x8 a_h[2], a_l[2], b_h[2], b_l[2];
#pragma unroll
            for (int q = 0; q < 2; ++q) {
                a_h[q] = *reinterpret_cast<const f16x8*>(&Ah[wm + q * 32 + lr][ko]);
                a_l[q] = *reinterpret_cast<const f16x8*>(&Al[wm + q * 32 + lr][ko]);
                b_h[q] = *reinterpret_cast<const f16x8*>(&Bh[wn + q * 32 + lr][ko]);
                b_l[q] = *reinterpret_cast<const f16x8*>(&Bl[wn + q * 32 + lr][ko]);
            }
#pragma unroll
            for (int i = 0; i < 2; ++i)
#pragma unroll
                for (int j = 0; j < 2; ++j) {
                    acc[i][j] = __builtin_amdgcn_mfma_f32_32x32x16_f16(
                        a_h[i], b_h[j], acc[i][j], 0, 0, 0);
                    acc[i][j] = __builtin_amdgcn_mfma_f32_32x32x16_f16(
                        a_h[i], b_l[j], acc[i][j], 0, 0, 0);
                    acc[i][j] = __builtin_amdgcn_mfma_f32_32x32x16_f16(
                        a_l[i], b_h[j], acc[i][j], 0, 0, 0);
                }
        }
    }

    // ---- fused chunk-local scan epilogue, two 128-column halves
    const int c = tid & 127;
    const int seg = tid >> 7;           // 0..3 row segments of 32
#pragma unroll
    for (int half = 0; half < 2; ++half) {
        __syncthreads();                // MFMA / previous-half readers done
        if ((wid >> 2) == half) {       // this wave's columns belong to half
#pragma unroll
            for (int i = 0; i < 2; ++i)
#pragma unroll
                for (int j = 0; j < 2; ++j)
#pragma unroll
                    for (int g = 0; g < 16; ++g) {
                        int row = wm + i * 32 + (g & 3) + 8 * (g >> 2) + 4 * lh;
                        hbuf[row][(wn & 127) + j * 32 + lr] = acc[i][j][g];
                    }
        }
        __syncthreads();
        const float a = Av[half * 128 + c];
        float sv[32];
        float h = 0.f;
#pragma unroll
        for (int r = 0; r < 32; ++r) {
            h = fmaf(h, a, hbuf[seg * 32 + r][c]);
            sv[r] = h;
        }
        segends[seg][c] = h;
        __syncthreads();
        float a32 = a;
#pragma unroll
        for (int i = 0; i < 5; ++i) a32 *= a32;   // a^32
        const float a64 = a32 * a32;
        float carry = 0.f;
        if (seg >= 1) carry = segends[seg - 1][c];
        if (seg >= 2) carry = fmaf(a32, segends[seg - 2][c], carry);
        if (seg >= 3) carry = fmaf(a64, segends[seg - 3][c], carry);
        float pw = a;
#pragma unroll
        for (int r = 0; r < 32; ++r) {
            float hc = fmaf(pw, carry, sv[r]);
            pw *= a;
            HL[(size_t)(row0 + seg * 32 + r) * SDIM + half * 128 + c] = hc;
            if (seg == 3 && r == 31)
                E[(size_t)ch * SDIM + half * 128 + c] = hc;   // chunk end
        }
    }
}

// ---------------------------------------------------------------------------
// K3: Y-tile GEMM ((h_local + A^{p+1} o H[ch]) @ C), correction fused into
// the A-staging path. Same tile geometry as K1.
// ---------------------------------------------------------------------------
__global__ __launch_bounds__(512, 4) void k3_gemm_out(
    const float* __restrict__ HL, const f16* __restrict__ ChT,
    const f16* __restrict__ ClT, const float* __restrict__ PW,
    const float* __restrict__ Hc, float* __restrict__ Y) {
    __shared__ __align__(16) f16 Ah[128][LDK], Al[128][LDK];
    __shared__ __align__(16) f16 Bh[256][LDK], Bl[256][LDK];

    const int ch = blockIdx.x;
    const int row0 = ch * CHUNK;
    const int tid = threadIdx.x;
    const int wid = tid >> 6, lane = tid & 63;
    const int wm = (wid & 1) * 64, wn = (wid >> 1) * 64;
    const int lr = lane & 31, kg8 = (lane >> 5) * 8, lh = lane >> 5;

    f32x16 acc[2][2] = {};

    for (int ks = 0; ks < 8; ++ks) {
        const int k0 = ks * 32;
        f32x4 xa[2];
        f16x8 bh[2], bl[2];
#pragma unroll
        for (int i = 0; i < 2; ++i) {
            int f = i * 512 + tid;
            int r = f >> 3, kq = (f & 7) * 4;
            f32x4 hv = *reinterpret_cast<const f32x4*>(
                &HL[(size_t)(row0 + r) * SDIM + k0 + kq]);
            f32x4 pw = *reinterpret_cast<const f32x4*>(&PW[(size_t)r * SDIM + k0 + kq]);
            f32x4 hcv = *reinterpret_cast<const f32x4*>(&Hc[(size_t)ch * SDIM + k0 + kq]);
            xa[i] = hv + pw * hcv;   // h_t = h_local + a^{p+1} * H_in
        }
#pragma unroll
        for (int i = 0; i < 2; ++i) {
            int f = i * 512 + tid;
            int r = f >> 2, ko = (f & 3) * 8;
            bh[i] = *reinterpret_cast<const f16x8*>(&ChT[(size_t)r * SDIM + k0 + ko]);
            bl[i] = *reinterpret_cast<const f16x8*>(&ClT[(size_t)r * SDIM + k0 + ko]);
        }
        __syncthreads();
#pragma unroll
        for (int i = 0; i < 2; ++i) {
            int f = i * 512 + tid;
            int r = f >> 3, kq = (f & 7) * 4;
            f16x4 hvv, lvv;
#pragma unroll
            for (int cc = 0; cc < 4; ++cc) {
                float x = xa[i][cc];
                f16 h = (f16)x;
                hvv[cc] = h;
                lvv[cc] = (f16)(x - (float)h);
            }
            *reinterpret_cast<f16x4*>(&Ah[r][kq]) = hvv;
            *reinterpret_cast<f16x4*>(&Al[r][kq]) = lvv;
        }
#pragma unroll
        for (int i = 0; i < 2; ++i) {
            int f = i * 512 + tid;
            int r = f >> 2, ko = (f & 3) * 8;
            *reinterpret_cast<f16x8*>(&Bh[r][ko]) = bh[i];
            *reinterpret_cast<f16x8*>(&Bl[r][ko]) = bl[i];
        }
        __syncthreads();
#pragma unroll
        for (int sl = 0; sl < 2; ++sl) {
            const int ko = sl * 16 + kg8;
            f16x8 a_h[2], a_l[2], b_h[2], b_l[2];
#pragma unroll
            for (int q = 0; q < 2; ++q) {
                a_h[q] = *reinterpret_cast<const f16x8*>(&Ah[wm + q * 32 + lr][ko]);
                a_l[q] = *reinterpret_cast<const f16x8*>(&Al[wm + q * 32 + lr][ko]);
                b_h[q] = *reinterpret_cast<const f16x8*>(&Bh[wn + q * 32 + lr][ko]);
                b_l[q] = *reinterpret_cast<const f16x8*>(&Bl[wn + q * 32 + lr][ko]);
            }
#pragma unroll
            for (int i = 0; i < 2; ++i)
#pragma unroll
                for (int j = 0; j < 2; ++j) {
                    acc[i][j] = __builtin_amdgcn_mfma_f32_32x32x16_f16(
                        a_h[i], b_h[j], acc[i][j], 0, 0, 0);
                    acc[i][j] = __builtin_amdgcn_mfma_f32_32x32x16_f16(
                        a_h[i], b_l[j], acc[i][j], 0, 0, 0);
                    acc[i][j] = __builtin_amdgcn_mfma_f32_32x32x16_f16(
                        a_l[i], b_h[j], acc[i][j], 0, 0, 0);
                }
        }
    }

#pragma unroll
    for (int i = 0; i < 2; ++i)
#pragma unroll
        for (int j = 0; j < 2; ++j)
#pragma unroll
            for (int g = 0; g < 16; ++g) {
                int row = row0 + wm + i * 32 + (g & 3) + 8 * (g >> 2) + 4 * lh;
                int col = wn + j * 32 + lr;
                Y[(size_t)row * SDIM + col] = acc[i][j][g];
            }
}

// ---------------------------------------------------------------------------
extern "C" void kernel_launch(void* const* d_in, const int* in_sizes, int n_in,
                              void* d_out, int out_size, void* d_ws, size_t ws_size,
                              hipStream_t stream) {
    const float* X  = (const float*)d_in[0];
    const float* Av = (const float*)d_in[1];
    const float* Bm = (const float*)d_in[2];
    const float* Cm = (const float*)d_in[3];
    const float* h0 = (const float*)d_in[4];
    float* Y = (float*)d_out;

    // ws layout: HL (64MB) | BhT BlT ChT ClT (4x128KB) | PW (128KB) | E | H
    char* w = (char*)d_ws;
    float* HL = (float*)w;                       w += (size_t)MTOT * SDIM * 4;
    f16* BhT = (f16*)w;                          w += 256 * 256 * 2;
    f16* BlT = (f16*)w;                          w += 256 * 256 * 2;
    f16* ChT = (f16*)w;                          w += 256 * 256 * 2;
    f16* ClT = (f16*)w;                          w += 256 * 256 * 2;
    float* PW = (float*)w;                       w += CHUNK * SDIM * 4;
    float* E  = (float*)w;                       w += (size_t)NCHTOT * SDIM * 4;
    float* H  = (float*)w;

    tsplit<<<dim3(4, 4), 256, 0, stream>>>(Bm, BhT, BlT);
    tsplit<<<dim3(4, 4), 256, 0, stream>>>(Cm, ChT, ClT);
    powA_kernel<<<1, 256, 0, stream>>>(Av, PW);

    k1_gemm_scan<<<NCHTOT, 512, 0, stream>>>(X, BhT, BlT, Av, HL, E);
    carries<<<BATCH, 256, 0, stream>>>(E, Av, h0, H);
    k3_gemm_out<<<NCHTOT, 512, 0, stream>>>(HL, ChT, ClT, PW, H, Y);
}